// Round 6
// baseline (1455.506 us; speedup 1.0000x reference)
//
#include <hip/hip_runtime.h>

// LightGCN propagation: 3 sparse layers over a fixed bipartite graph.
// R8: layer-kernel software pipelining (preprocessing unchanged from R6):
//  (a) edge-stream prefetch: tile k+1's edge records load while tile k's
//      gathers are in flight -> edge latency off the per-tile critical path.
//      (R7 was latency-bound: VALUBusy 30%, HBM 48%, occ 78% - none saturated.)
//  (b) MODE2 recompose loads (init/prev/own) hoisted before the gather loop
//      (were dependent-serial after the reduce).
// Loop structure: pipelined while >=2 tiles remain -> one drain tile ->
// predicated tail tile (R7's clamp+zero-weight).

#define EMB 64
// 512 rows per bucket: localrow = 9 bits, col < 300000 -> 19 bits, packs in 28.
#define BSH 9
#define BROWS 512

__global__ __launch_bounds__(1024) void coarse_hist(const int* __restrict__ rows,
                                                    int* __restrict__ cnt, int nnz, int NB) {
    __shared__ int lcnt[1024];
    int t = threadIdx.x;
    lcnt[t] = 0;
    __syncthreads();
    int stride = gridDim.x * 1024;
    for (int i = blockIdx.x * 1024 + t; i < nnz; i += stride)
        atomicAdd(&lcnt[rows[i] >> BSH], 1);
    __syncthreads();
    int c = lcnt[t];
    if (t < NB && c > 0) atomicAdd(&cnt[t], c);
}

// single block: exclusive scan over NB (<=1024) bucket counts
__global__ void scan_buckets(const int* __restrict__ cnt, int* __restrict__ base,
                             int* __restrict__ cursor, int* __restrict__ row_ptr,
                             int NB, int N) {
    __shared__ int sblk[256];
    int t = threadIdx.x;
    int a[4]; int tsum = 0;
#pragma unroll
    for (int k = 0; k < 4; ++k) { int b = t * 4 + k; a[k] = (b < NB) ? cnt[b] : 0; tsum += a[k]; }
    int x = tsum; sblk[t] = x; __syncthreads();
    for (int off = 1; off < 256; off <<= 1) {
        int y = (t >= off) ? sblk[t - off] : 0;
        __syncthreads();
        x += y; sblk[t] = x; __syncthreads();
    }
    int run = x - tsum;   // exclusive prefix for this thread's 4 entries
#pragma unroll
    for (int k = 0; k < 4; ++k) {
        int b = t * 4 + k;
        if (b < NB) { base[b] = run; cursor[b] = run; }
        run += a[k];
    }
    if (t == 255) { base[NB] = x; row_ptr[N] = x; }   // x == nnz
}

// Bucket-grouped binning: count chunk's edges per bucket in LDS, reserve one
// contiguous range per touched bucket, place records. 1024 thr x VPT 16.
#define BIN_VPT 16
__global__ __launch_bounds__(1024) void bin_kernel(
    const int* __restrict__ rows, const int* __restrict__ cols,
    const float* __restrict__ vals, int* __restrict__ cursor,
    int2* __restrict__ binned, int nnz, int NB)
{
    __shared__ int lcnt[1024];
    __shared__ int gbase[1024];
    int t = threadIdx.x;
    int base0 = blockIdx.x * (1024 * BIN_VPT);
    lcnt[t] = 0;
    __syncthreads();
#pragma unroll 4
    for (int j = 0; j < BIN_VPT; ++j) {
        int i = base0 + j * 1024 + t;
        if (i < nnz) atomicAdd(&lcnt[rows[i] >> BSH], 1);
    }
    __syncthreads();
    {
        int c = lcnt[t];
        if (t < NB && c > 0) gbase[t] = atomicAdd(&cursor[t], c);
        lcnt[t] = 0;
    }
    __syncthreads();
#pragma unroll 4
    for (int j = 0; j < BIN_VPT; ++j) {
        int i = base0 + j * 1024 + t;
        if (i < nnz) {
            int r = rows[i];
            int b = r >> BSH;
            int lp = atomicAdd(&lcnt[b], 1);
            binned[gbase[b] + lp] =
                make_int2(((r - (b << BSH)) << 19) | cols[i], __float_as_int(vals[i]));
        }
    }
}

// One WG per bucket: LDS row-hist + scan -> row_ptr; scatter to final CSR
// slots via LDS cursors (L2-resident window, zero global atomics).
__global__ __launch_bounds__(1024) void finalize_kernel(
    const int* __restrict__ base, const int2* __restrict__ binned,
    int* __restrict__ row_ptr, int2* __restrict__ edges, int N)
{
    __shared__ int lhist[BROWS];
    __shared__ int lpref[BROWS];
    __shared__ int sblk[256];
    int b = blockIdx.x;
    int t = threadIdx.x;
    int s = base[b], e = base[b + 1];
    if (t < BROWS) lhist[t] = 0;
    __syncthreads();
    for (int i = s + t; i < e; i += 1024)
        atomicAdd(&lhist[binned[i].x >> 19], 1);
    __syncthreads();
    int a0 = 0, a1 = 0, tsum = 0, x = 0;
    if (t < 256) {
        a0 = lhist[2 * t]; a1 = lhist[2 * t + 1];
        tsum = a0 + a1; x = tsum; sblk[t] = x;
    }
    __syncthreads();
    for (int off = 1; off < 256; off <<= 1) {
        int y = (t < 256 && t >= off) ? sblk[t - off] : 0;
        __syncthreads();
        if (t < 256) { x += y; sblk[t] = x; }
        __syncthreads();
    }
    if (t < 256) { lpref[2 * t] = x - tsum; lpref[2 * t + 1] = x - tsum + a0; }
    __syncthreads();
    if (t < BROWS) {
        int gr = (b << BSH) + t;
        int slot = s + lpref[t];
        if (gr < N) row_ptr[gr] = slot;
        lhist[t] = slot;   // reuse as global-slot cursor
    }
    __syncthreads();
    for (int i = s + t; i < e; i += 1024) {
        int2 rec = binned[i];
        int lr = rec.x >> 19;
        int pos = atomicAdd(&lhist[lr], 1);
        edges[pos] = make_int2(rec.x & 0x7FFFF, rec.y);
    }
}

#define FMA4(acc, v, g) \
    acc.x = fmaf(v, g.x, acc.x); acc.y = fmaf(v, g.y, acc.y); \
    acc.z = fmaf(v, g.z, acc.z); acc.w = fmaf(v, g.w, acc.w);

// One wave per row. 16-lane groups: group g handles edge i+g (+4,+8,+12),
// each lane holds 4 dims (float4): one gather instr = 4 edges' rows = 1KB.
// MODE 0: embout = sum (gather from opposite table, table-local via cofs)
// MODE 1: embout = sum (gather from embA)
// MODE 2: acc = 0.25*(init + prev + own + sum)  (gather from embB)
template<int MODE>
__global__ __launch_bounds__(256) void layer_kernel(
    const int* __restrict__ row_ptr, const int2* __restrict__ edges,
    const float4* __restrict__ src4, int cofs,
    const float4* __restrict__ init4, const float4* __restrict__ prev4,
    float4* __restrict__ embout4, float4* __restrict__ acc4,
    int row0, int nrows)
{
    int wid = (int)((blockIdx.x * blockDim.x + threadIdx.x) >> 6);
    if (wid >= nrows) return;
    int row  = row0 + wid;
    int lane = threadIdx.x & 63;
    int grp  = lane >> 4;
    int sub  = lane & 15;
    int s = row_ptr[row], e = row_ptr[row + 1];

    // MODE2 recompose streams: issue before the gather loop (independent).
    float4 rb = make_float4(0.f, 0.f, 0.f, 0.f);
    float4 rpa = rb, rpb = rb;
    if (MODE == 2 && grp == 0) {
        rb  = init4[(size_t)wid * 16 + sub];
        rpa = prev4[(size_t)row * 16 + sub];
        rpb = src4[(size_t)row * 16 + sub];
    }

    float4 a0 = make_float4(0.f, 0.f, 0.f, 0.f);
    float4 a1 = a0, a2 = a0, a3 = a0;

    int i = s;
    if (i + 32 <= e) {
        // software-pipelined: edges for tile k+1 load under tile k's gathers
        int2 c0 = edges[i + grp];
        int2 c1 = edges[i + 4 + grp];
        int2 c2 = edges[i + 8 + grp];
        int2 c3 = edges[i + 12 + grp];
        for (; i + 32 <= e; i += 16) {
            float4 g0 = src4[(size_t)(c0.x - cofs) * 16 + sub];
            float4 g1 = src4[(size_t)(c1.x - cofs) * 16 + sub];
            float4 g2 = src4[(size_t)(c2.x - cofs) * 16 + sub];
            float4 g3 = src4[(size_t)(c3.x - cofs) * 16 + sub];
            int2 n0 = edges[i + 16 + grp];
            int2 n1 = edges[i + 20 + grp];
            int2 n2 = edges[i + 24 + grp];
            int2 n3 = edges[i + 28 + grp];
            float v0 = __int_as_float(c0.y);
            float v1 = __int_as_float(c1.y);
            float v2 = __int_as_float(c2.y);
            float v3 = __int_as_float(c3.y);
            FMA4(a0, v0, g0); FMA4(a1, v1, g1);
            FMA4(a2, v2, g2); FMA4(a3, v3, g3);
            c0 = n0; c1 = n1; c2 = n2; c3 = n3;
        }
        // drain tile (c* holds a full loaded tile at i)
        {
            float4 g0 = src4[(size_t)(c0.x - cofs) * 16 + sub];
            float4 g1 = src4[(size_t)(c1.x - cofs) * 16 + sub];
            float4 g2 = src4[(size_t)(c2.x - cofs) * 16 + sub];
            float4 g3 = src4[(size_t)(c3.x - cofs) * 16 + sub];
            float v0 = __int_as_float(c0.y);
            float v1 = __int_as_float(c1.y);
            float v2 = __int_as_float(c2.y);
            float v3 = __int_as_float(c3.y);
            FMA4(a0, v0, g0); FMA4(a1, v1, g1);
            FMA4(a2, v2, g2); FMA4(a3, v3, g3);
            i += 16;
        }
    } else if (i + 16 <= e) {
        int2 c0 = edges[i + grp];
        int2 c1 = edges[i + 4 + grp];
        int2 c2 = edges[i + 8 + grp];
        int2 c3 = edges[i + 12 + grp];
        float4 g0 = src4[(size_t)(c0.x - cofs) * 16 + sub];
        float4 g1 = src4[(size_t)(c1.x - cofs) * 16 + sub];
        float4 g2 = src4[(size_t)(c2.x - cofs) * 16 + sub];
        float4 g3 = src4[(size_t)(c3.x - cofs) * 16 + sub];
        float v0 = __int_as_float(c0.y);
        float v1 = __int_as_float(c1.y);
        float v2 = __int_as_float(c2.y);
        float v3 = __int_as_float(c3.y);
        FMA4(a0, v0, g0); FMA4(a1, v1, g1);
        FMA4(a2, v2, g2); FMA4(a3, v3, g3);
        i += 16;
    }
    if (i < e) {
        // predicated tail tile: clamp index (address stays valid), zero weight
        int e1 = e - 1;
        int j0 = i + grp, j1 = j0 + 4, j2 = j0 + 8, j3 = j0 + 12;
        int2 c0 = edges[min(j0, e1)];
        int2 c1 = edges[min(j1, e1)];
        int2 c2 = edges[min(j2, e1)];
        int2 c3 = edges[min(j3, e1)];
        float4 g0 = src4[(size_t)(c0.x - cofs) * 16 + sub];
        float4 g1 = src4[(size_t)(c1.x - cofs) * 16 + sub];
        float4 g2 = src4[(size_t)(c2.x - cofs) * 16 + sub];
        float4 g3 = src4[(size_t)(c3.x - cofs) * 16 + sub];
        float v0 = (j0 < e) ? __int_as_float(c0.y) : 0.f;
        float v1 = (j1 < e) ? __int_as_float(c1.y) : 0.f;
        float v2 = (j2 < e) ? __int_as_float(c2.y) : 0.f;
        float v3 = (j3 < e) ? __int_as_float(c3.y) : 0.f;
        FMA4(a0, v0, g0); FMA4(a1, v1, g1);
        FMA4(a2, v2, g2); FMA4(a3, v3, g3);
    }

    float4 t;
    t.x = (a0.x + a1.x) + (a2.x + a3.x);
    t.y = (a0.y + a1.y) + (a2.y + a3.y);
    t.z = (a0.z + a1.z) + (a2.z + a3.z);
    t.w = (a0.w + a1.w) + (a2.w + a3.w);
    t.x += __shfl_xor(t.x, 16); t.x += __shfl_xor(t.x, 32);
    t.y += __shfl_xor(t.y, 16); t.y += __shfl_xor(t.y, 32);
    t.z += __shfl_xor(t.z, 16); t.z += __shfl_xor(t.z, 32);
    t.w += __shfl_xor(t.w, 16); t.w += __shfl_xor(t.w, 32);

    if (grp == 0) {
        size_t o = (size_t)row * 16 + sub;
        if (MODE != 2) {
            embout4[o] = t;
        } else {
            float4 r;
            r.x = 0.25f * (((rb.x + rpa.x) + rpb.x) + t.x);
            r.y = 0.25f * (((rb.y + rpa.y) + rpb.y) + t.y);
            r.z = 0.25f * (((rb.z + rpa.z) + rpb.z) + t.z);
            r.w = 0.25f * (((rb.w + rpa.w) + rpb.w) + t.w);
            acc4[o] = r;
        }
    }
}

extern "C" void kernel_launch(void* const* d_in, const int* in_sizes, int n_in,
                              void* d_out, int out_size, void* d_ws, size_t ws_size,
                              hipStream_t stream) {
    const float* ue   = (const float*)d_in[0];
    const float* ie   = (const float*)d_in[1];
    const float* vals = (const float*)d_in[2];
    const int*   rows = (const int*)d_in[3];
    const int*   cols = (const int*)d_in[4];

    int nu  = in_sizes[0] / EMB;
    int ni  = in_sizes[1] / EMB;
    int N   = nu + ni;
    int nnz = in_sizes[2];
    int M   = N + 1;
    int NB  = (N + BROWS - 1) >> BSH;   // 586 buckets for N=300000 (<=1024)

    // workspace carve-out (256B aligned)
    char*  w   = (char*)d_ws;
    size_t off = 0;
    auto alloc = [&](size_t bytes) -> void* {
        void* p = w + off;
        off = (off + bytes + 255) & ~(size_t)255;
        return p;
    };
    float* embA    = (float*)alloc((size_t)N * EMB * sizeof(float));
    float* embB    = (float*)alloc((size_t)N * EMB * sizeof(float));
    int2*  edges   = (int2*) alloc((size_t)nnz * sizeof(int2));
    int*   cnt     = (int*)  alloc(1024 * sizeof(int));
    int*   base    = (int*)  alloc(1025 * sizeof(int));
    int*   cursor  = (int*)  alloc(1024 * sizeof(int));
    int*   row_ptr = (int*)  alloc((size_t)M * sizeof(int));
    float* acc     = (float*)d_out;   // final output

    // binned records (nnz * 8B = 80MB) alias embA+embB (153.6MB), which are
    // dead until layer0 runs (after finalize_kernel has consumed binned).
    int2* binned = (int2*)embA;

    hipMemsetAsync(cnt, 0, 1024 * sizeof(int), stream);

    coarse_hist<<<512, 1024, 0, stream>>>(rows, cnt, nnz, NB);
    scan_buckets<<<1, 256, 0, stream>>>(cnt, base, cursor, row_ptr, NB, N);

    int bgrid = (nnz + 1024 * BIN_VPT - 1) / (1024 * BIN_VPT);
    bin_kernel<<<bgrid, 1024, 0, stream>>>(rows, cols, vals, cursor, binned, nnz, NB);
    finalize_kernel<<<NB, 1024, 0, stream>>>(base, binned, row_ptr, edges, N);

    const float4* ue4   = (const float4*)ue;
    const float4* ie4   = (const float4*)ie;
    float4* embA4 = (float4*)embA;
    float4* embB4 = (float4*)embB;
    float4* acc4  = (float4*)acc;

    int ugrid = (nu * 64 + 255) / 256;
    int igrid = (ni * 64 + 255) / 256;

    // layer 0: user rows gather item table; item rows gather user table.
    layer_kernel<0><<<ugrid, 256, 0, stream>>>(row_ptr, edges, ie4, nu, nullptr, nullptr, embA4, nullptr, 0,  nu);
    layer_kernel<0><<<igrid, 256, 0, stream>>>(row_ptr, edges, ue4, 0,  nullptr, nullptr, embA4, nullptr, nu, ni);
    // layer 1
    layer_kernel<1><<<ugrid, 256, 0, stream>>>(row_ptr, edges, embA4, 0, nullptr, nullptr, embB4, nullptr, 0,  nu);
    layer_kernel<1><<<igrid, 256, 0, stream>>>(row_ptr, edges, embA4, 0, nullptr, nullptr, embB4, nullptr, nu, ni);
    // layer 2: acc = 0.25*(e0 + embA + embB + sum)
    layer_kernel<2><<<ugrid, 256, 0, stream>>>(row_ptr, edges, embB4, 0, ue4, embA4, nullptr, acc4, 0,  nu);
    layer_kernel<2><<<igrid, 256, 0, stream>>>(row_ptr, edges, embB4, 0, ie4, embA4, nullptr, acc4, nu, ni);
}

// Round 7
// 1100.136 us; speedup vs baseline: 1.3230x; 1.3230x over previous
//
#include <hip/hip_runtime.h>
#include <hip/hip_fp16.h>

// LightGCN propagation: 3 sparse layers over a fixed bipartite graph.
// R9: fp16 embedding storage for gathered tables. R6-R8 showed the layers
// pinned at ~3.8-3.9 TB/s effective fetch across three different inner-loop
// structures (VALUBusy 30%, occ 72-78%, HBM 47%) -> random-256B-gather
// memory-path roofline, not issue-bound. Only lever: fewer bytes.
//  - e0 staged to fp16 (inH), e1/e2 stored fp16 (embA_h/embB_h):
//    gather traffic 256->128 B/edge, embout writes halved, tables (38.4MB)
//    L2/L3-retain better.
//  - gather arithmetic stays fp32 (convert after load); MODE2's direct e0
//    term reads the ORIGINAL fp32 tables, so only e1/e2/e3 see storage
//    rounding: predicted absmax ~1e-5.
//  - layer0 now gathers one contiguous fp16 table (absolute col, no cofs).
// Preprocessing (two-level bucket sort) unchanged from R6.

#define EMB 64
// 512 rows per bucket: localrow = 9 bits, col < 300000 -> 19 bits, packs in 28.
#define BSH 9
#define BROWS 512

__global__ __launch_bounds__(1024) void coarse_hist(const int* __restrict__ rows,
                                                    int* __restrict__ cnt, int nnz, int NB) {
    __shared__ int lcnt[1024];
    int t = threadIdx.x;
    lcnt[t] = 0;
    __syncthreads();
    int stride = gridDim.x * 1024;
    for (int i = blockIdx.x * 1024 + t; i < nnz; i += stride)
        atomicAdd(&lcnt[rows[i] >> BSH], 1);
    __syncthreads();
    int c = lcnt[t];
    if (t < NB && c > 0) atomicAdd(&cnt[t], c);
}

// single block: exclusive scan over NB (<=1024) bucket counts
__global__ void scan_buckets(const int* __restrict__ cnt, int* __restrict__ base,
                             int* __restrict__ cursor, int* __restrict__ row_ptr,
                             int NB, int N) {
    __shared__ int sblk[256];
    int t = threadIdx.x;
    int a[4]; int tsum = 0;
#pragma unroll
    for (int k = 0; k < 4; ++k) { int b = t * 4 + k; a[k] = (b < NB) ? cnt[b] : 0; tsum += a[k]; }
    int x = tsum; sblk[t] = x; __syncthreads();
    for (int off = 1; off < 256; off <<= 1) {
        int y = (t >= off) ? sblk[t - off] : 0;
        __syncthreads();
        x += y; sblk[t] = x; __syncthreads();
    }
    int run = x - tsum;   // exclusive prefix for this thread's 4 entries
#pragma unroll
    for (int k = 0; k < 4; ++k) {
        int b = t * 4 + k;
        if (b < NB) { base[b] = run; cursor[b] = run; }
        run += a[k];
    }
    if (t == 255) { base[NB] = x; row_ptr[N] = x; }   // x == nnz
}

// Bucket-grouped binning: count chunk's edges per bucket in LDS, reserve one
// contiguous range per touched bucket, place records. 1024 thr x VPT 16.
#define BIN_VPT 16
__global__ __launch_bounds__(1024) void bin_kernel(
    const int* __restrict__ rows, const int* __restrict__ cols,
    const float* __restrict__ vals, int* __restrict__ cursor,
    int2* __restrict__ binned, int nnz, int NB)
{
    __shared__ int lcnt[1024];
    __shared__ int gbase[1024];
    int t = threadIdx.x;
    int base0 = blockIdx.x * (1024 * BIN_VPT);
    lcnt[t] = 0;
    __syncthreads();
#pragma unroll 4
    for (int j = 0; j < BIN_VPT; ++j) {
        int i = base0 + j * 1024 + t;
        if (i < nnz) atomicAdd(&lcnt[rows[i] >> BSH], 1);
    }
    __syncthreads();
    {
        int c = lcnt[t];
        if (t < NB && c > 0) gbase[t] = atomicAdd(&cursor[t], c);
        lcnt[t] = 0;
    }
    __syncthreads();
#pragma unroll 4
    for (int j = 0; j < BIN_VPT; ++j) {
        int i = base0 + j * 1024 + t;
        if (i < nnz) {
            int r = rows[i];
            int b = r >> BSH;
            int lp = atomicAdd(&lcnt[b], 1);
            binned[gbase[b] + lp] =
                make_int2(((r - (b << BSH)) << 19) | cols[i], __float_as_int(vals[i]));
        }
    }
}

// One WG per bucket: LDS row-hist + scan -> row_ptr; scatter to final CSR
// slots via LDS cursors (L2-resident window, zero global atomics).
__global__ __launch_bounds__(1024) void finalize_kernel(
    const int* __restrict__ base, const int2* __restrict__ binned,
    int* __restrict__ row_ptr, int2* __restrict__ edges, int N)
{
    __shared__ int lhist[BROWS];
    __shared__ int lpref[BROWS];
    __shared__ int sblk[256];
    int b = blockIdx.x;
    int t = threadIdx.x;
    int s = base[b], e = base[b + 1];
    if (t < BROWS) lhist[t] = 0;
    __syncthreads();
    for (int i = s + t; i < e; i += 1024)
        atomicAdd(&lhist[binned[i].x >> 19], 1);
    __syncthreads();
    int a0 = 0, a1 = 0, tsum = 0, x = 0;
    if (t < 256) {
        a0 = lhist[2 * t]; a1 = lhist[2 * t + 1];
        tsum = a0 + a1; x = tsum; sblk[t] = x;
    }
    __syncthreads();
    for (int off = 1; off < 256; off <<= 1) {
        int y = (t < 256 && t >= off) ? sblk[t - off] : 0;
        __syncthreads();
        if (t < 256) { x += y; sblk[t] = x; }
        __syncthreads();
    }
    if (t < 256) { lpref[2 * t] = x - tsum; lpref[2 * t + 1] = x - tsum + a0; }
    __syncthreads();
    if (t < BROWS) {
        int gr = (b << BSH) + t;
        int slot = s + lpref[t];
        if (gr < N) row_ptr[gr] = slot;
        lhist[t] = slot;   // reuse as global-slot cursor
    }
    __syncthreads();
    for (int i = s + t; i < e; i += 1024) {
        int2 rec = binned[i];
        int lr = rec.x >> 19;
        int pos = atomicAdd(&lhist[lr], 1);
        edges[pos] = make_int2(rec.x & 0x7FFFF, rec.y);
    }
}

__device__ __forceinline__ float4 h4_to_f4(uint2 u) {
    __half2 h0 = *reinterpret_cast<const __half2*>(&u.x);
    __half2 h1 = *reinterpret_cast<const __half2*>(&u.y);
    float2 f0 = __half22float2(h0);
    float2 f1 = __half22float2(h1);
    return make_float4(f0.x, f0.y, f1.x, f1.y);
}

__device__ __forceinline__ uint2 f4_to_h4(float4 f) {
    __half2 h0 = __floats2half2_rn(f.x, f.y);
    __half2 h1 = __floats2half2_rn(f.z, f.w);
    uint2 u;
    u.x = *reinterpret_cast<const unsigned*>(&h0);
    u.y = *reinterpret_cast<const unsigned*>(&h1);
    return u;
}

// fp32 table -> fp16 table (4 elems per thread, grid-stride)
__global__ __launch_bounds__(256) void f2h_kernel(const float4* __restrict__ src,
                                                 uint2* __restrict__ dst, int n4) {
    int stride = gridDim.x * 256;
    for (int i = blockIdx.x * 256 + threadIdx.x; i < n4; i += stride)
        dst[i] = f4_to_h4(src[i]);
}

#define FMA4(acc, v, g) \
    acc.x = fmaf(v, g.x, acc.x); acc.y = fmaf(v, g.y, acc.y); \
    acc.z = fmaf(v, g.z, acc.z); acc.w = fmaf(v, g.w, acc.w);

#define GATHER4(gg0, gg1, gg2, gg3, cc0, cc1, cc2, cc3) \
    float4 gg0 = h4_to_f4(srcH[(size_t)cc0.x * 16 + sub]); \
    float4 gg1 = h4_to_f4(srcH[(size_t)cc1.x * 16 + sub]); \
    float4 gg2 = h4_to_f4(srcH[(size_t)cc2.x * 16 + sub]); \
    float4 gg3 = h4_to_f4(srcH[(size_t)cc3.x * 16 + sub]);

// One wave per row. 16-lane groups: group g handles edge i+g (+4,+8,+12),
// each lane holds 4 dims. Gather = uint2 (4 halves, 8B/lane, 128B/row).
// MODE 0/1: emboutH = sum (fp16). MODE 2: acc4 = 0.25*(e0_fp32 + prev + own + sum).
template<int MODE>
__global__ __launch_bounds__(256) void layer_kernel(
    const int* __restrict__ row_ptr, const int2* __restrict__ edges,
    const uint2* __restrict__ srcH,
    const float4* __restrict__ init4,   // MODE2: fp32 e0 table (table-local)
    const uint2* __restrict__ prevH,    // MODE2: e1 (fp16, row-global)
    uint2* __restrict__ emboutH, float4* __restrict__ acc4,
    int row0, int nrows)
{
    int wid = (int)((blockIdx.x * blockDim.x + threadIdx.x) >> 6);
    if (wid >= nrows) return;
    int row  = row0 + wid;
    int lane = threadIdx.x & 63;
    int grp  = lane >> 4;
    int sub  = lane & 15;
    int s = row_ptr[row], e = row_ptr[row + 1];

    // MODE2 recompose streams: issue before the gather loop (independent).
    float4 rb = make_float4(0.f, 0.f, 0.f, 0.f);
    float4 rpa = rb, rpb = rb;
    if (MODE == 2 && grp == 0) {
        rb  = init4[(size_t)wid * 16 + sub];                 // e0, fp32
        rpa = h4_to_f4(prevH[(size_t)row * 16 + sub]);       // e1
        rpb = h4_to_f4(srcH[(size_t)row * 16 + sub]);        // e2 (own row)
    }

    float4 a0 = make_float4(0.f, 0.f, 0.f, 0.f);
    float4 a1 = a0, a2 = a0, a3 = a0;

    int i = s;
    if (i + 32 <= e) {
        // software-pipelined: edges for tile k+1 load under tile k's gathers
        int2 c0 = edges[i + grp];
        int2 c1 = edges[i + 4 + grp];
        int2 c2 = edges[i + 8 + grp];
        int2 c3 = edges[i + 12 + grp];
        for (; i + 32 <= e; i += 16) {
            GATHER4(g0, g1, g2, g3, c0, c1, c2, c3)
            int2 n0 = edges[i + 16 + grp];
            int2 n1 = edges[i + 20 + grp];
            int2 n2 = edges[i + 24 + grp];
            int2 n3 = edges[i + 28 + grp];
            float v0 = __int_as_float(c0.y);
            float v1 = __int_as_float(c1.y);
            float v2 = __int_as_float(c2.y);
            float v3 = __int_as_float(c3.y);
            FMA4(a0, v0, g0); FMA4(a1, v1, g1);
            FMA4(a2, v2, g2); FMA4(a3, v3, g3);
            c0 = n0; c1 = n1; c2 = n2; c3 = n3;
        }
        {   // drain tile
            GATHER4(g0, g1, g2, g3, c0, c1, c2, c3)
            float v0 = __int_as_float(c0.y);
            float v1 = __int_as_float(c1.y);
            float v2 = __int_as_float(c2.y);
            float v3 = __int_as_float(c3.y);
            FMA4(a0, v0, g0); FMA4(a1, v1, g1);
            FMA4(a2, v2, g2); FMA4(a3, v3, g3);
            i += 16;
        }
    } else if (i + 16 <= e) {
        int2 c0 = edges[i + grp];
        int2 c1 = edges[i + 4 + grp];
        int2 c2 = edges[i + 8 + grp];
        int2 c3 = edges[i + 12 + grp];
        GATHER4(g0, g1, g2, g3, c0, c1, c2, c3)
        float v0 = __int_as_float(c0.y);
        float v1 = __int_as_float(c1.y);
        float v2 = __int_as_float(c2.y);
        float v3 = __int_as_float(c3.y);
        FMA4(a0, v0, g0); FMA4(a1, v1, g1);
        FMA4(a2, v2, g2); FMA4(a3, v3, g3);
        i += 16;
    }
    if (i < e) {
        // predicated tail tile: clamp index (address stays valid), zero weight
        int e1 = e - 1;
        int j0 = i + grp, j1 = j0 + 4, j2 = j0 + 8, j3 = j0 + 12;
        int2 c0 = edges[min(j0, e1)];
        int2 c1 = edges[min(j1, e1)];
        int2 c2 = edges[min(j2, e1)];
        int2 c3 = edges[min(j3, e1)];
        GATHER4(g0, g1, g2, g3, c0, c1, c2, c3)
        float v0 = (j0 < e) ? __int_as_float(c0.y) : 0.f;
        float v1 = (j1 < e) ? __int_as_float(c1.y) : 0.f;
        float v2 = (j2 < e) ? __int_as_float(c2.y) : 0.f;
        float v3 = (j3 < e) ? __int_as_float(c3.y) : 0.f;
        FMA4(a0, v0, g0); FMA4(a1, v1, g1);
        FMA4(a2, v2, g2); FMA4(a3, v3, g3);
    }

    float4 t;
    t.x = (a0.x + a1.x) + (a2.x + a3.x);
    t.y = (a0.y + a1.y) + (a2.y + a3.y);
    t.z = (a0.z + a1.z) + (a2.z + a3.z);
    t.w = (a0.w + a1.w) + (a2.w + a3.w);
    t.x += __shfl_xor(t.x, 16); t.x += __shfl_xor(t.x, 32);
    t.y += __shfl_xor(t.y, 16); t.y += __shfl_xor(t.y, 32);
    t.z += __shfl_xor(t.z, 16); t.z += __shfl_xor(t.z, 32);
    t.w += __shfl_xor(t.w, 16); t.w += __shfl_xor(t.w, 32);

    if (grp == 0) {
        size_t o = (size_t)row * 16 + sub;
        if (MODE != 2) {
            emboutH[o] = f4_to_h4(t);
        } else {
            float4 r;
            r.x = 0.25f * (((rb.x + rpa.x) + rpb.x) + t.x);
            r.y = 0.25f * (((rb.y + rpa.y) + rpb.y) + t.y);
            r.z = 0.25f * (((rb.z + rpa.z) + rpb.z) + t.z);
            r.w = 0.25f * (((rb.w + rpa.w) + rpb.w) + t.w);
            acc4[o] = r;
        }
    }
}

extern "C" void kernel_launch(void* const* d_in, const int* in_sizes, int n_in,
                              void* d_out, int out_size, void* d_ws, size_t ws_size,
                              hipStream_t stream) {
    const float* ue   = (const float*)d_in[0];
    const float* ie   = (const float*)d_in[1];
    const float* vals = (const float*)d_in[2];
    const int*   rows = (const int*)d_in[3];
    const int*   cols = (const int*)d_in[4];

    int nu  = in_sizes[0] / EMB;
    int ni  = in_sizes[1] / EMB;
    int N   = nu + ni;
    int nnz = in_sizes[2];
    int M   = N + 1;
    int NB  = (N + BROWS - 1) >> BSH;   // 586 buckets for N=300000 (<=1024)

    // workspace carve-out (256B aligned)
    char*  w   = (char*)d_ws;
    size_t off = 0;
    auto alloc = [&](size_t bytes) -> void* {
        void* p = w + off;
        off = (off + bytes + 255) & ~(size_t)255;
        return p;
    };
    uint2* inH     = (uint2*)alloc((size_t)N * 16 * sizeof(uint2));  // e0 fp16 [user|item]
    uint2* embA_h  = (uint2*)alloc((size_t)N * 16 * sizeof(uint2));  // e1 fp16
    uint2* embB_h  = (uint2*)alloc((size_t)N * 16 * sizeof(uint2));  // e2 fp16
    int2*  edges   = (int2*) alloc((size_t)nnz * sizeof(int2));
    int*   cnt     = (int*)  alloc(1024 * sizeof(int));
    int*   base    = (int*)  alloc(1025 * sizeof(int));
    int*   cursor  = (int*)  alloc(1024 * sizeof(int));
    int*   row_ptr = (int*)  alloc((size_t)M * sizeof(int));
    float* acc     = (float*)d_out;   // final output

    // binned records (nnz*8B = 80MB) alias inH+embA_h+embB_h (115.2MB), all
    // dead until after finalize_kernel (f2h + layer0 run after it).
    int2* binned = (int2*)inH;

    hipMemsetAsync(cnt, 0, 1024 * sizeof(int), stream);

    coarse_hist<<<512, 1024, 0, stream>>>(rows, cnt, nnz, NB);
    scan_buckets<<<1, 256, 0, stream>>>(cnt, base, cursor, row_ptr, NB, N);

    int bgrid = (nnz + 1024 * BIN_VPT - 1) / (1024 * BIN_VPT);
    bin_kernel<<<bgrid, 1024, 0, stream>>>(rows, cols, vals, cursor, binned, nnz, NB);
    finalize_kernel<<<NB, 1024, 0, stream>>>(base, binned, row_ptr, edges, N);

    // stage e0 to fp16: inH = [ue | ie]
    f2h_kernel<<<1024, 256, 0, stream>>>((const float4*)ue, inH, nu * 16);
    f2h_kernel<<<1024, 256, 0, stream>>>((const float4*)ie, inH + (size_t)nu * 16, ni * 16);

    const float4* ue4 = (const float4*)ue;
    const float4* ie4 = (const float4*)ie;
    float4* acc4 = (float4*)acc;

    int ugrid = (nu * 64 + 255) / 256;
    int igrid = (ni * 64 + 255) / 256;

    // layer 0: gathers from fp16 e0 table (absolute col index)
    layer_kernel<0><<<ugrid, 256, 0, stream>>>(row_ptr, edges, inH, nullptr, nullptr, embA_h, nullptr, 0,  nu);
    layer_kernel<0><<<igrid, 256, 0, stream>>>(row_ptr, edges, inH, nullptr, nullptr, embA_h, nullptr, nu, ni);
    // layer 1
    layer_kernel<1><<<ugrid, 256, 0, stream>>>(row_ptr, edges, embA_h, nullptr, nullptr, embB_h, nullptr, 0,  nu);
    layer_kernel<1><<<igrid, 256, 0, stream>>>(row_ptr, edges, embA_h, nullptr, nullptr, embB_h, nullptr, nu, ni);
    // layer 2: acc = 0.25*(e0_fp32 + e1 + e2 + sum)
    layer_kernel<2><<<ugrid, 256, 0, stream>>>(row_ptr, edges, embB_h, ue4, embA_h, nullptr, acc4, 0,  nu);
    layer_kernel<2><<<igrid, 256, 0, stream>>>(row_ptr, edges, embB_h, ie4, embA_h, nullptr, acc4, nu, ni);
}